// Round 8
// baseline (407.555 us; speedup 1.0000x reference)
//
#include <hip/hip_runtime.h>
#include <hip/hip_bf16.h>
#include <stdint.h>

#define N_NODES 50000
#define N_EDGES 800000
#define N_GRAPHS 512
#define NSUB 16            // c-subbuckets per graph (c>>12, c<50000 -> 0..12)
#define NBUCK (N_GRAPHS * NSUB)   // 8192

// ---------- helpers ----------
__device__ __forceinline__ unsigned f2sort(float f) {
    unsigned u = __float_as_uint(f);
    return (u & 0x80000000u) ? ~u : (u | 0x80000000u);   // monotonic f32 -> u32
}
__device__ __forceinline__ float sort2f(unsigned u) {
    return __uint_as_float((u & 0x80000000u) ? (u ^ 0x80000000u) : ~u);
}

// ---------- K0: (g, c-window) histogram + node_start ----------
__global__ __launch_bounds__(256) void k0_count(const int* __restrict__ ei,
                                                const int* __restrict__ batch,
                                                unsigned* __restrict__ subdeg,
                                                int* __restrict__ node_start) {
    __shared__ unsigned hist[NBUCK];       // 32 KB
    const int tid = threadIdx.x;
    for (int i = tid; i < NBUCK; i += 256) hist[i] = 0;
    __syncthreads();
    const int e0 = blockIdx.x * 4096;
    #pragma unroll 4
    for (int j = 0; j < 16; ++j) {
        int e = e0 + j * 256 + tid;
        if (e < N_EDGES) {
            int r = ei[e], c = ei[N_EDGES + e];
            atomicAdd(&hist[batch[r] * NSUB + (c >> 12)], 1u);
        }
    }
    #pragma unroll 4
    for (int j = 0; j < 16; ++j) {
        int i = e0 + j * 256 + tid;
        if (i < N_NODES) {
            int b = batch[i];
            if (i == 0) { for (int g2 = 0; g2 <= b; ++g2) node_start[g2] = 0; }
            else { int bp = batch[i - 1]; for (int g2 = bp + 1; g2 <= b; ++g2) node_start[g2] = i; }
            if (i == N_NODES - 1) { for (int g2 = b + 1; g2 <= N_GRAPHS; ++g2) node_start[g2] = N_NODES; }
        }
    }
    __syncthreads();
    for (int i = tid; i < NBUCK; i += 256) {
        unsigned h = hist[i];
        if (h) atomicAdd(&subdeg[i], h);
    }
}

// ---------- K3: scan 8192 subbucket counts; derive per-graph deg/start/kk ----------
__global__ __launch_bounds__(1024) void k3_scan(const unsigned* __restrict__ subdeg,
                                                unsigned* __restrict__ substart,
                                                unsigned* __restrict__ deg,
                                                unsigned* __restrict__ start,
                                                unsigned* __restrict__ kkv) {
    __shared__ unsigned lds[1024];
    const int t = threadIdx.x;
    unsigned v[8], s = 0;
    #pragma unroll
    for (int j = 0; j < 8; ++j) { v[j] = subdeg[t * 8 + j]; s += v[j]; }
    lds[t] = s;
    for (int off = 1; off < 1024; off <<= 1) {
        __syncthreads();
        unsigned u = (t >= off) ? lds[t - off] : 0u;
        __syncthreads();
        lds[t] += u;
    }
    __syncthreads();
    unsigned run = lds[t] - s;             // exclusive prefix
    #pragma unroll
    for (int j = 0; j < 8; ++j) { substart[t * 8 + j] = run; run += v[j]; }
    if (t == 1023) substart[NBUCK] = lds[1023];   // total == N_EDGES
    __syncthreads();
    if (t < N_GRAPHS) {
        unsigned st0 = substart[t * NSUB];
        unsigned d = substart[(t + 1) * NSUB] - st0;
        start[t] = st0;
        deg[t] = d;
        kkv[t] = (d + 1u) >> 1;            // ceil(0.5*deg)
    }
}

// ---------- K4a: scatter edges into (g, c-window) buckets ----------
__global__ __launch_bounds__(256) void k4a_scatter(const int* __restrict__ ei,
                                                   const int* __restrict__ batch,
                                                   const unsigned* __restrict__ substart,
                                                   unsigned* __restrict__ subcursor,
                                                   unsigned* __restrict__ rcbuck,
                                                   unsigned* __restrict__ ebuck) {
    int e = blockIdx.x * 256 + threadIdx.x;         // grid exact
    int r = ei[e], c = ei[N_EDGES + e];
    int b = batch[r] * NSUB + (c >> 12);
    unsigned rank = atomicAdd(&subcursor[b], 1u);
    unsigned pos = substart[b] + rank;
    rcbuck[pos] = (unsigned)r | ((unsigned)c << 16);
    ebuck[pos]  = (unsigned)e;
}

// ---------- K1: P = emb@W1a + b1, Q = emb@W1b ----------
__global__ __launch_bounds__(256) void k1_gemm(const float* __restrict__ emb,
                                               const float* __restrict__ W1,
                                               const float* __restrict__ b1,
                                               float* __restrict__ P,
                                               float* __restrict__ Q) {
    __shared__ float As[64][68];
    __shared__ float Bs[64][128];
    const int tid = threadIdx.x;
    const int v0  = blockIdx.x * 64;
    const int cy  = blockIdx.y;

    if (v0 + 64 <= N_NODES) {
        const float* srcA = emb + (size_t)v0 * 64;
        for (int idx = tid * 4; idx < 4096; idx += 1024) {
            float4 x = *(const float4*)(srcA + idx);
            int r = idx >> 6, k = idx & 63;
            As[k + 0][r] = x.x; As[k + 1][r] = x.y; As[k + 2][r] = x.z; As[k + 3][r] = x.w;
        }
    } else {
        for (int idx = tid * 4; idx < 4096; idx += 1024) {
            int r = idx >> 6, k = idx & 63;
            int v = v0 + r; if (v >= N_NODES) v = N_NODES - 1;
            float4 x = *(const float4*)(emb + (size_t)v * 64 + k);
            As[k + 0][r] = x.x; As[k + 1][r] = x.y; As[k + 2][r] = x.z; As[k + 3][r] = x.w;
        }
    }
    for (int idx = tid * 4; idx < 64 * 128; idx += 1024) {
        int k = idx >> 7, c = idx & 127;
        int jj = cy * 128 + c;
        const float* src = (jj < 256) ? (W1 + (size_t)k * 256 + jj)
                                      : (W1 + (size_t)(64 + k) * 256 + (jj - 256));
        *(float4*)&Bs[k][c] = *(const float4*)src;
    }
    __syncthreads();

    const int cgrp = tid & 31;
    const int rgrp = tid >> 5;
    float acc[8][4];
    #pragma unroll
    for (int r = 0; r < 8; ++r) { acc[r][0]=0.f; acc[r][1]=0.f; acc[r][2]=0.f; acc[r][3]=0.f; }

    #pragma unroll 8
    for (int k = 0; k < 64; ++k) {
        float4 b = *(const float4*)&Bs[k][cgrp * 4];
        const float4* ap = (const float4*)&As[k][rgrp * 8];
        float4 a01 = ap[0], a23 = ap[1];
        float av[8] = {a01.x, a01.y, a01.z, a01.w, a23.x, a23.y, a23.z, a23.w};
        #pragma unroll
        for (int r = 0; r < 8; ++r) {
            acc[r][0] = fmaf(av[r], b.x, acc[r][0]);
            acc[r][1] = fmaf(av[r], b.y, acc[r][1]);
            acc[r][2] = fmaf(av[r], b.z, acc[r][2]);
            acc[r][3] = fmaf(av[r], b.w, acc[r][3]);
        }
    }

    const int jj0 = cy * 128 + cgrp * 4;
    float4 badd = {0.f, 0.f, 0.f, 0.f};
    if (jj0 < 256) badd = *(const float4*)(b1 + jj0);
    #pragma unroll
    for (int r = 0; r < 8; ++r) {
        int v = v0 + rgrp * 8 + r;
        if (v < N_NODES) {
            float4 o = {acc[r][0] + badd.x, acc[r][1] + badd.y,
                        acc[r][2] + badd.z, acc[r][3] + badd.w};
            float* dst = (jj0 < 256) ? (P + (size_t)v * 256 + jj0)
                                     : (Q + (size_t)v * 256 + (jj0 - 256));
            *(float4*)dst = o;
        }
    }
}

// ---------- K2: per-graph scoring, 8-edge ILP per wave, P staged in LDS ----------
__global__ __launch_bounds__(512, 4) void k2_edge(const float* __restrict__ P,
                                                  const float* __restrict__ Q,
                                                  const unsigned* __restrict__ rcbuck,
                                                  const unsigned* __restrict__ ebuck,
                                                  const unsigned* __restrict__ deg,
                                                  const unsigned* __restrict__ start,
                                                  const int* __restrict__ node_start,
                                                  const float* __restrict__ W2,
                                                  const float* __restrict__ b2,
                                                  float* __restrict__ att,
                                                  unsigned* __restrict__ minmax,
                                                  int ldsrows) {
    extern __shared__ float4 lds4[];
    const int g = blockIdx.x;
    const int n = (int)deg[g];
    if (n == 0) return;
    const int st = (int)start[g];
    const int n0 = node_start[g];
    const int nr = node_start[g + 1] - n0;
    const int ncap = nr < ldsrows ? nr : ldsrows;
    const int tid = threadIdx.x;

    const float4* Pg4 = (const float4*)(P + (size_t)n0 * 256);
    for (int u = tid; u < ncap * 64; u += 512) lds4[u] = Pg4[u];
    __syncthreads();

    const int lane = tid & 63;
    const int w = tid >> 6;          // 8 waves
    const int j0 = lane * 4;
    const float4 w2v = *(const float4*)(W2 + j0);
    const float b2v = b2[0];
    float vmin = __builtin_inff(), vmax = -__builtin_inff();

    const int noct = (n + 7) >> 3;
    for (int oi = w; oi < noct; oi += 8) {
        const int i0 = st + oi * 8;
        int cnt = n - oi * 8; if (cnt > 8) cnt = 8;
        // +8 tail pad on rcbuck/ebuck keeps these reads in-bounds; garbage
        // lanes are masked by cnt (poison 0xAAAA < N_NODES, so addresses safe)
        uint4 rcA = *(const uint4*)(rcbuck + i0);
        uint4 rcB = *(const uint4*)(rcbuck + i0 + 4);
        uint4 evA = *(const uint4*)(ebuck + i0);
        uint4 evB = *(const uint4*)(ebuck + i0 + 4);
        unsigned rc[8] = {rcA.x, rcA.y, rcA.z, rcA.w, rcB.x, rcB.y, rcB.z, rcB.w};
        unsigned ev[8] = {evA.x, evA.y, evA.z, evA.w, evB.x, evB.y, evB.z, evB.w};

        float4 p[8], q[8];
        #pragma unroll
        for (int j = 0; j < 8; ++j) {
            int r = (int)(rc[j] & 0xFFFFu);
            int c = (int)(rc[j] >> 16);
            int rl = r - n0;
            q[j] = *(const float4*)(Q + (size_t)c * 256 + j0);
            p[j] = (rl < ncap && rl >= 0) ? lds4[rl * 64 + lane]
                                          : *(const float4*)(P + (size_t)r * 256 + j0);
        }

        float part[8];
        #pragma unroll
        for (int j = 0; j < 8; ++j) {
            float s0 = fmaxf(p[j].x + q[j].x, 0.f);
            float s1 = fmaxf(p[j].y + q[j].y, 0.f);
            float s2 = fmaxf(p[j].z + q[j].z, 0.f);
            float s3 = fmaxf(p[j].w + q[j].w, 0.f);
            part[j] = fmaf(s3, w2v.w, fmaf(s2, w2v.z, fmaf(s1, w2v.y, s0 * w2v.x)));
        }
        #pragma unroll
        for (int off = 32; off; off >>= 1) {
            #pragma unroll
            for (int j = 0; j < 8; ++j) part[j] += __shfl_xor(part[j], off, 64);
        }
        // lane j stores edge j (compile-time lane select, no scratch)
        float av = part[0]; unsigned ew = ev[0];
        #pragma unroll
        for (int j = 1; j < 8; ++j) if (lane == j) { av = part[j]; ew = ev[j]; }
        if (lane < cnt) att[ew] = av + b2v;

        #pragma unroll
        for (int j = 0; j < 8; ++j) {
            if (j < cnt) {
                float a = part[j] + b2v;
                vmin = fminf(vmin, a); vmax = fmaxf(vmax, a);
            }
        }
    }
    if (lane == 0) {
        atomicMin(&minmax[0], f2sort(vmin));
        atomicMax(&minmax[1], f2sort(vmax));
    }
}

// ---------- K5: radix-select top-K per graph (exact (key,e) order semantics) ----------
__global__ __launch_bounds__(256) void k5_select(const unsigned* __restrict__ deg,
                                                 const unsigned* __restrict__ start,
                                                 const unsigned* __restrict__ kk,
                                                 const float* __restrict__ att,
                                                 const unsigned* __restrict__ ebuck,
                                                 const unsigned* __restrict__ rcbuck,
                                                 const unsigned* __restrict__ minmax,
                                                 unsigned char* __restrict__ keep,
                                                 unsigned char* __restrict__ flagC,
                                                 unsigned char* __restrict__ flagS) {
    __shared__ unsigned kbuf[4096];
    __shared__ unsigned hist[256];
    __shared__ unsigned sh_b, sh_excl, sh_cnt;
    const int g = blockIdx.x, t = threadIdx.x;
    int n = (int)deg[g]; if (n > 4096) n = 4096;
    if (n == 0) return;
    const unsigned st = start[g];
    const float fmin = sort2f(minmax[0]);
    const float fmax = sort2f(minmax[1]);
    const float denom = (fmax - fmin) + 1e-12f;
    const float gf = (float)g;
    for (int i = t; i < n; i += 256) {
        float a = att[ebuck[st + i]];
        float nq = (a - fmin) / denom;       // replicate ref f32 division
        float mq = nq - gf;                  // replicate ref's quantizing subtraction
        kbuf[i] = ~f2sort(mq);               // ascending == ref's descending-norm order
    }
    const unsigned K = kk[g];                // 1..n

    // --- select K-th smallest key (MSB radix, 4 passes) ---
    unsigned lo = 0, prefix = 0, meq = 0;
    for (int byte = 3; byte >= 0; --byte) {
        __syncthreads();
        hist[t] = 0;
        __syncthreads();
        const int shAbove = (byte + 1) * 8;
        for (int i = t; i < n; i += 256) {
            unsigned k = kbuf[i];
            bool ok = (byte == 3) || ((k >> shAbove) == (prefix >> shAbove));
            if (ok) atomicAdd(&hist[(k >> (byte * 8)) & 0xFFu], 1u);
        }
        __syncthreads();
        unsigned v = hist[t];
        for (int off = 1; off < 256; off <<= 1) {
            __syncthreads();
            unsigned u = (t >= off) ? hist[t - off] : 0u;
            __syncthreads();
            hist[t] += u;
        }
        __syncthreads();
        unsigned incl = hist[t], excl = incl - v;
        unsigned target = K - lo;            // >= 1
        if (excl < target && target <= incl) { sh_b = (unsigned)t; sh_excl = excl; sh_cnt = v; }
        __syncthreads();
        prefix |= sh_b << (byte * 8);
        lo += sh_excl;
        meq = sh_cnt;
    }
    const unsigned T32 = prefix;
    const unsigned tneed = K - lo;           // 1..meq
    bool keepAllTies = (tneed == meq);

    // --- among ties (key==T32), select tneed-th smallest e (3 passes; e < 2^20) ---
    unsigned E_t = 0xFFFFFFFFu;
    if (!keepAllTies) {
        unsigned elo = 0, eprefix = 0;
        for (int byte = 2; byte >= 0; --byte) {
            __syncthreads();
            hist[t] = 0;
            __syncthreads();
            const int shAbove = (byte + 1) * 8;
            for (int i = t; i < n; i += 256) {
                if (kbuf[i] == T32) {
                    unsigned e = ebuck[st + i];
                    bool ok = (byte == 2) || ((e >> shAbove) == (eprefix >> shAbove));
                    if (ok) atomicAdd(&hist[(e >> (byte * 8)) & 0xFFu], 1u);
                }
            }
            __syncthreads();
            unsigned v = hist[t];
            for (int off = 1; off < 256; off <<= 1) {
                __syncthreads();
                unsigned u = (t >= off) ? hist[t - off] : 0u;
                __syncthreads();
                hist[t] += u;
            }
            __syncthreads();
            unsigned incl = hist[t], excl = incl - v;
            unsigned target = tneed - elo;
            if (excl < target && target <= incl) { sh_b = (unsigned)t; sh_excl = excl; }
            __syncthreads();
            eprefix |= sh_b << (byte * 8);
            elo += sh_excl;
        }
        E_t = eprefix;                       // tneed-th smallest e among ties
    }

    // --- mark keep (e-order, scattered but L2-absorbed) + endpoint flags ---
    __syncthreads();
    for (int i = t; i < n; i += 256) {
        unsigned k = kbuf[i];
        unsigned e = ebuck[st + i];
        bool kp = (k < T32) || (k == T32 && (keepAllTies || e <= E_t));
        keep[e] = kp ? 1 : 0;
        unsigned rc = rcbuck[st + i];
        int r = (int)(rc & 0xFFFFu), c = (int)(rc >> 16);
        if (kp) { flagC[r] = 1; flagC[c] = 1; }
        else    { flagS[r] = 1; flagS[c] = 1; }
    }
}

// ---------- K7: node-id compaction scan ----------
__global__ __launch_bounds__(1024) void k7_nodescan(const unsigned char* __restrict__ flagC,
                                                    const unsigned char* __restrict__ flagS,
                                                    int* __restrict__ nidxC,
                                                    int* __restrict__ nidxS) {
    const unsigned char* fl = blockIdx.x ? flagS : flagC;
    int* nx = blockIdx.x ? nidxS : nidxC;
    __shared__ int lds[1024];
    const int t = threadIdx.x;
    const int CH = (N_NODES + 1023) / 1024;   // 49
    const int base = t * CH;
    int s = 0;
    for (int i = 0; i < CH; ++i) { int v = base + i; if (v < N_NODES) s += fl[v]; }
    lds[t] = s;
    for (int off = 1; off < 1024; off <<= 1) {
        __syncthreads();
        int v = (t >= off) ? lds[t - off] : 0;
        __syncthreads();
        lds[t] += v;
    }
    __syncthreads();
    int run = lds[t] - s;
    for (int i = 0; i < CH; ++i) {
        int v = base + i;
        if (v < N_NODES) {
            if (fl[v]) { nx[v] = run; run++; } else nx[v] = -1;
        }
    }
}

// ---------- K8: outputs, fully coalesced (att/keep already e-ordered) ----------
__global__ __launch_bounds__(256) void k8_out(const float* __restrict__ att,
                                              const unsigned char* __restrict__ keep,
                                              const int* __restrict__ ei,
                                              const int* __restrict__ nidxC,
                                              const int* __restrict__ nidxS,
                                              float* __restrict__ out) {
    int e = blockIdx.x * 256 + threadIdx.x;       // grid exact
    float a = att[e];
    int kp = keep[e];
    int r = ei[e], c = ei[N_EDGES + e];
    out[e]               = a;
    out[N_EDGES + e]     = kp ? a : 0.f;
    out[2 * N_EDGES + e] = kp ? 0.f : -a;
    if (kp) {
        out[3 * N_EDGES + e] = (float)nidxC[r];
        out[4 * N_EDGES + e] = (float)nidxC[c];
        out[5 * N_EDGES + e] = -1.f;
        out[6 * N_EDGES + e] = -1.f;
    } else {
        out[3 * N_EDGES + e] = -1.f;
        out[4 * N_EDGES + e] = -1.f;
        out[5 * N_EDGES + e] = (float)nidxS[r];
        out[6 * N_EDGES + e] = (float)nidxS[c];
    }
}

extern "C" void kernel_launch(void* const* d_in, const int* in_sizes, int n_in,
                              void* d_out, int out_size, void* d_ws, size_t ws_size,
                              hipStream_t stream) {
    const float* emb   = (const float*)d_in[0];
    const int*   ei    = (const int*)d_in[1];
    const int*   batch = (const int*)d_in[2];
    const float* W1    = (const float*)d_in[3];
    const float* b1    = (const float*)d_in[4];
    const float* W2    = (const float*)d_in[5];
    const float* b2    = (const float*)d_in[6];
    float* out = (float*)d_out;

    char* ws = (char*)d_ws;
    size_t off = 0;
    auto alloc = [&](size_t bytes) -> void* {
        off = (off + 255) & ~(size_t)255;
        void* p = ws + off;
        off += bytes;
        return p;
    };

    float* P              = (float*)alloc((size_t)N_NODES * 256 * 4);   // 51.2 MB
    float* Q              = (float*)alloc((size_t)N_NODES * 256 * 4);   // 51.2 MB
    float* att            = (float*)alloc((size_t)N_EDGES * 4);
    unsigned* rcbuck      = (unsigned*)alloc(((size_t)N_EDGES + 8) * 4);
    unsigned* ebuck       = (unsigned*)alloc(((size_t)N_EDGES + 8) * 4);
    unsigned char* keep   = (unsigned char*)alloc(N_EDGES);
    unsigned char* flags2 = (unsigned char*)alloc((size_t)2 * N_NODES);  // C|S contiguous
    unsigned char* flagC  = flags2;
    unsigned char* flagS  = flags2 + N_NODES;
    int* nidxC            = (int*)alloc((size_t)N_NODES * 4);
    int* nidxS            = (int*)alloc((size_t)N_NODES * 4);
    // zeroed meta block: subdeg(8192) subcursor(8192) deg(512) start(512) kk(512) minmax(2)
    unsigned* meta        = (unsigned*)alloc((2 * NBUCK + 3 * 512 + 2) * 4);
    unsigned* subdeg      = meta;
    unsigned* subcursor   = meta + NBUCK;
    unsigned* deg         = meta + 2 * NBUCK;
    unsigned* start       = meta + 2 * NBUCK + 512;
    unsigned* kk          = meta + 2 * NBUCK + 1024;
    unsigned* minmax      = meta + 2 * NBUCK + 1536;
    unsigned* substart    = (unsigned*)alloc((NBUCK + 1) * 4);   // written by k3
    int* node_start       = (int*)alloc(513 * 4);

    const int EB = (N_EDGES + 255) / 256;       // 3125 (exact)
    const int SB = (N_EDGES + 4095) / 4096;     // 196 count blocks

    hipMemsetAsync(meta, 0, (2 * NBUCK + 3 * 512 + 2) * 4, stream);
    hipMemsetAsync(minmax, 0xFF, 4, stream);                  // min acc = UINT_MAX
    hipMemsetAsync(flags2, 0, (size_t)2 * N_NODES, stream);

    int ldsrows = 78;                                         // 78 KB -> 2 blocks/CU
    if (hipFuncSetAttribute((const void*)k2_edge,
                            hipFuncAttributeMaxDynamicSharedMemorySize,
                            78 * 1024) != hipSuccess) {
        ldsrows = 56;
    }
    const size_t shbytes = (size_t)ldsrows * 1024;

    k0_count<<<SB, 256, 0, stream>>>(ei, batch, subdeg, node_start);
    k3_scan<<<1, 1024, 0, stream>>>(subdeg, substart, deg, start, kk);
    k4a_scatter<<<EB, 256, 0, stream>>>(ei, batch, substart, subcursor, rcbuck, ebuck);

    dim3 g1((N_NODES + 63) / 64, 4);
    k1_gemm<<<g1, 256, 0, stream>>>(emb, W1, b1, P, Q);

    k2_edge<<<N_GRAPHS, 512, shbytes, stream>>>(P, Q, rcbuck, ebuck, deg, start,
                                                node_start, W2, b2, att, minmax, ldsrows);

    k5_select<<<N_GRAPHS, 256, 0, stream>>>(deg, start, kk, att, ebuck, rcbuck,
                                            minmax, keep, flagC, flagS);
    k7_nodescan<<<2, 1024, 0, stream>>>(flagC, flagS, nidxC, nidxS);
    k8_out<<<EB, 256, 0, stream>>>(att, keep, ei, nidxC, nidxS, out);
}